// Round 10
// baseline (344.816 us; speedup 1.0000x reference)
//
#include <hip/hip_runtime.h>
#include <hip/hip_bf16.h>

// GraphSAGE 2-layer forward on MI355X — round 10.
// Edge-parallel segmented-sum aggregation: one wave per 64 consecutive CSR
// edges; 64 lanes cover one 256B bf16 row per load (wave-uniform scalar row
// address via readlane); 16 independent row loads in flight per sub-batch;
// dst-change flush -> f32 atomicAdd into aggf[N][128] (avg ~4 flushes/wave).
// Fixes round-8 agg's per-node imbalance/prologue and round-9's 4x VALU
// overhead (agg4: VALUBusy 85%, VGPR 24 -> serialized loads).
// GEMM reads the f32 agg operand and converts to bf16 fragments in-register.

#define BLK 256

typedef __attribute__((ext_vector_type(8))) short short8;
typedef __attribute__((ext_vector_type(8))) unsigned short ushort8;
typedef __attribute__((ext_vector_type(4))) float f32x4;

__device__ inline unsigned short f2bf(float f) {
    unsigned int u = __builtin_bit_cast(unsigned int, f);
    u += 0x7fffu + ((u >> 16) & 1u);  // RNE (inputs finite)
    return (unsigned short)(u >> 16);
}
__device__ inline float bf2f(unsigned short h) {
    return __builtin_bit_cast(float, ((unsigned int)h) << 16);
}

// ---------------- CSR build ----------------

// XCD-partitioned degree count (blockIdx&7 owns a dst octant -> atomics stay
// in one XCD's L2; fixes scattered-atomic line ping-pong).
__global__ __launch_bounds__(BLK) void deg_xcd_kernel(const int* __restrict__ dst, int E,
                                                      int* __restrict__ deg,
                                                      int range, int CH) {
    const int oct = blockIdx.x & 7;
    const int chunk = blockIdx.x >> 3;
    const int lo = oct * range, hi = lo + range;
    int e0 = chunk * CH;
    int e1 = min(E, e0 + CH);
    for (int e = e0 + threadIdx.x; e < e1; e += BLK) {
        int d = dst[e];
        if (d >= lo && d < hi) atomicAdd(&deg[d], 1);
    }
}

__global__ __launch_bounds__(BLK) void partial_sum_kernel(const int* __restrict__ deg,
                                                          int n, int* __restrict__ partials) {
    __shared__ int s[BLK];
    int t = threadIdx.x;
    int idx = blockIdx.x * BLK + t;
    s[t] = (idx < n) ? deg[idx] : 0;
    __syncthreads();
    for (int o = BLK / 2; o > 0; o >>= 1) {
        if (t < o) s[t] += s[t + o];
        __syncthreads();
    }
    if (t == 0) partials[blockIdx.x] = s[0];
}

__global__ __launch_bounds__(BLK) void scan_partials_kernel(int* __restrict__ partials, int n) {
    __shared__ int s[BLK];
    int t = threadIdx.x;
    int v = (t < n) ? partials[t] : 0;
    s[t] = v;
    __syncthreads();
    int sum = v;
    for (int o = 1; o < BLK; o <<= 1) {
        int other = (t >= o) ? s[t - o] : 0;
        __syncthreads();
        sum += other;
        s[t] = sum;
        __syncthreads();
    }
    if (t < n) partials[t] = sum - v;  // exclusive
}

// also emits inv_deg = 1/max(deg,1) for the aggregation flushes
__global__ __launch_bounds__(BLK) void chunk_scan_kernel(const int* __restrict__ deg,
                                                         const int* __restrict__ partials,
                                                         int n, int* __restrict__ row_start,
                                                         float* __restrict__ inv_deg) {
    __shared__ int s[BLK];
    int t = threadIdx.x;
    int idx = blockIdx.x * BLK + t;
    int v = (idx < n) ? deg[idx] : 0;
    s[t] = v;
    __syncthreads();
    int sum = v;
    for (int o = 1; o < BLK; o <<= 1) {
        int other = (t >= o) ? s[t - o] : 0;
        __syncthreads();
        sum += other;
        s[t] = sum;
        __syncthreads();
    }
    if (idx < n) {
        row_start[idx] = (sum - v) + partials[blockIdx.x];
        inv_deg[idx] = 1.0f / fmaxf((float)v, 1.0f);
    }
}

// XCD-partitioned fill; also records csr_dst (needed by edge-parallel agg).
__global__ __launch_bounds__(BLK) void fill_xcd_kernel(const int* __restrict__ src,
                                                       const int* __restrict__ dst, int E,
                                                       const int* __restrict__ row_start,
                                                       int* __restrict__ cursor,
                                                       int* __restrict__ csr_src,
                                                       int* __restrict__ csr_dst,
                                                       int range, int CH) {
    const int oct = blockIdx.x & 7;
    const int chunk = blockIdx.x >> 3;
    const int lo = oct * range, hi = lo + range;
    int e0 = chunk * CH;
    int e1 = min(E, e0 + CH);
    for (int e = e0 + threadIdx.x; e < e1; e += BLK) {
        int d = dst[e];
        if (d >= lo && d < hi) {
            int pos = atomicAdd(&cursor[d], 1);
            int p = row_start[d] + pos;
            csr_src[p] = src[e];
            csr_dst[p] = d;
        }
    }
}

// ---------------- prep: x f32 -> bf16 row-major + all W packs, one dispatch ----
// P[((kb*(Ncol/16)+n16)*64 + lane)*8 + j] = W[kb*32 + (lane>>4)*8 + j][n16*16 + (lane&15)]

__global__ __launch_bounds__(BLK) void prep_kernel(const float* __restrict__ x,
                                                   unsigned short* __restrict__ xb, int nquad,
                                                   const float* __restrict__ W1l,
                                                   const float* __restrict__ W1r,
                                                   const float* __restrict__ W2l,
                                                   const float* __restrict__ W2r,
                                                   unsigned short* __restrict__ P1l,
                                                   unsigned short* __restrict__ P1r,
                                                   unsigned short* __restrict__ P2l,
                                                   unsigned short* __restrict__ P2r) {
    int t = blockIdx.x * BLK + threadIdx.x;
    if (t < nquad) {
        float4 v = ((const float4*)x)[t];
        ushort4 o;
        o.x = f2bf(v.x); o.y = f2bf(v.y); o.z = f2bf(v.z); o.w = f2bf(v.w);
        ((ushort4*)xb)[t] = o;
        return;
    }
    int w = t - nquad;
    const float* W;
    unsigned short* P;
    int Ncol, local;
    if (w < 16384)      { W = W1l; P = P1l; Ncol = 128; local = w; }
    else if (w < 32768) { W = W1r; P = P1r; Ncol = 128; local = w - 16384; }
    else if (w < 40960) { W = W2l; P = P2l; Ncol = 64;  local = w - 32768; }
    else if (w < 49152) { W = W2r; P = P2r; Ncol = 64;  local = w - 40960; }
    else return;
    int j = local & 7;
    int lane = (local >> 3) & 63;
    int rest = local >> 9;
    int nt = Ncol >> 4;
    int n16 = rest % nt, kb = rest / nt;
    int k = kb * 32 + (lane >> 4) * 8 + j;
    int c = n16 * 16 + (lane & 15);
    P[local] = f2bf(W[(size_t)k * Ncol + c]);
}

// ---------------- edge-parallel segmented mean aggregation ----------------
// Wave handles 64 consecutive CSR edges. Lanes hold 64 src/dst indices
// (coalesced load); per 16-edge sub-batch: prefetch 16 full rows (scalar row
// base via readlane -> 16 independent loads), then accumulate; on dst change
// (wave-uniform) flush acc*inv_deg via f32 atomicAdd (~4 flushes/wave).

__global__ __launch_bounds__(BLK) void agg_edge_kernel(const unsigned short* __restrict__ feat,
                                                       const int* __restrict__ csr_src,
                                                       const int* __restrict__ csr_dst,
                                                       const float* __restrict__ inv_deg,
                                                       float* __restrict__ aggf, int E) {
    const int wave = threadIdx.x >> 6, lane = threadIdx.x & 63;
    const int e0 = (blockIdx.x * (BLK / 64) + wave) * 64;
    if (e0 >= E) return;
    int m = E - e0 < 64 ? E - e0 : 64;
    int srcv = csr_src[e0 + (lane < m ? lane : m - 1)];
    int dstv = csr_dst[e0 + (lane < m ? lane : m - 1)];
    const unsigned int* fp = (const unsigned int*)feat;  // 64 uints (256B) per row

    int d_cur = __builtin_amdgcn_readlane(dstv, 0);
    float a0 = 0.f, a1 = 0.f;

#pragma unroll
    for (int b = 0; b < 64; b += 16) {
        int bm = m - b;
        if (bm <= 0) break;
        if (bm > 16) bm = 16;
        unsigned int v[16];
#pragma unroll
        for (int j = 0; j < 16; j++) {
            int sl = b + (j < bm ? j : bm - 1);
            int s = __builtin_amdgcn_readlane(srcv, sl);
            v[j] = fp[(size_t)s * 64 + lane];
        }
#pragma unroll
        for (int j = 0; j < 16; j++) {
            if (j < bm) {  // wave-uniform
                int d = __builtin_amdgcn_readlane(dstv, b + j);
                if (d != d_cur) {  // wave-uniform segment boundary
                    float inv = inv_deg[d_cur];
                    atomicAdd(&aggf[(size_t)d_cur * 128 + lane * 2],     a0 * inv);
                    atomicAdd(&aggf[(size_t)d_cur * 128 + lane * 2 + 1], a1 * inv);
                    d_cur = d;
                    a0 = 0.f; a1 = 0.f;
                }
                a0 += bf2f((unsigned short)v[j]);
                a1 += bf2f((unsigned short)(v[j] >> 16));
            }
        }
    }
    float inv = inv_deg[d_cur];
    atomicAdd(&aggf[(size_t)d_cur * 128 + lane * 2],     a0 * inv);
    atomicAdd(&aggf[(size_t)d_cur * 128 + lane * 2 + 1], a1 * inv);
}

// ---------------- MFMA dual GEMM: out = A1f@Pl + A2@Pr + bias ----------------
// A1f: f32 [M][128] (agg result; converted to bf16 fragments in-register).
// A2: bf16 [M][128]. A-frag: lane row=lane&15 (+16), k=(lane>>4)*8+j (16B).
// D-frag: col=lane&15, row=(lane>>4)*4+i.

__device__ inline short8 ld_a_f32(const float* __restrict__ A, int row, int kbase) {
    const float4* p = (const float4*)(A + (size_t)row * 128 + kbase);
    float4 x0 = p[0], x1 = p[1];
    ushort8 r;
    r[0] = f2bf(x0.x); r[1] = f2bf(x0.y); r[2] = f2bf(x0.z); r[3] = f2bf(x0.w);
    r[4] = f2bf(x1.x); r[5] = f2bf(x1.y); r[6] = f2bf(x1.z); r[7] = f2bf(x1.w);
    return __builtin_bit_cast(short8, r);
}

template <int NCOL, bool RELU, bool OUT_BF16>
__global__ __launch_bounds__(BLK) void gemm_dual_kernel(const float* __restrict__ A1f,
                                                        const unsigned short* __restrict__ A2,
                                                        const unsigned short* __restrict__ Pl,
                                                        const unsigned short* __restrict__ Pr,
                                                        const float* __restrict__ bias,
                                                        void* __restrict__ outp, int M) {
    constexpr int NT = NCOL / 16;
    const int wave = threadIdx.x >> 6, lane = threadIdx.x & 63;
    const int r0 = blockIdx.x * 128 + wave * 32;
    const int arow = lane & 15, kgrp = lane >> 4;

    f32x4 acc[2][NT];
#pragma unroll
    for (int h = 0; h < 2; h++)
#pragma unroll
        for (int n = 0; n < NT; n++) acc[h][n] = (f32x4){0.f, 0.f, 0.f, 0.f};

    const int ra = min(r0 + arow, M - 1);
    const int rb = min(r0 + 16 + arow, M - 1);

    // mat 0: A1f (f32 -> bf16 in-register)
#pragma unroll
    for (int kb = 0; kb < 4; ++kb) {
        short8 afa = ld_a_f32(A1f, ra, kgrp * 8 + kb * 32);
        short8 afb = ld_a_f32(A1f, rb, kgrp * 8 + kb * 32);
        const unsigned short* Pk = Pl + (size_t)kb * NT * 512 + lane * 8;
#pragma unroll
        for (int n = 0; n < NT; ++n) {
            short8 wf = *(const short8*)(Pk + n * 512);
            acc[0][n] = __builtin_amdgcn_mfma_f32_16x16x32_bf16(afa, wf, acc[0][n], 0, 0, 0);
            acc[1][n] = __builtin_amdgcn_mfma_f32_16x16x32_bf16(afb, wf, acc[1][n], 0, 0, 0);
        }
    }
    // mat 1: A2 (bf16)
    {
        const unsigned short* Aa = A2 + (size_t)ra * 128 + kgrp * 8;
        const unsigned short* Ab = A2 + (size_t)rb * 128 + kgrp * 8;
#pragma unroll
        for (int kb = 0; kb < 4; ++kb) {
            short8 afa = *(const short8*)(Aa + kb * 32);
            short8 afb = *(const short8*)(Ab + kb * 32);
            const unsigned short* Pk = Pr + (size_t)kb * NT * 512 + lane * 8;
#pragma unroll
            for (int n = 0; n < NT; ++n) {
                short8 wf = *(const short8*)(Pk + n * 512);
                acc[0][n] = __builtin_amdgcn_mfma_f32_16x16x32_bf16(afa, wf, acc[0][n], 0, 0, 0);
                acc[1][n] = __builtin_amdgcn_mfma_f32_16x16x32_bf16(afb, wf, acc[1][n], 0, 0, 0);
            }
        }
    }

#pragma unroll
    for (int n = 0; n < NT; ++n) {
        int col = n * 16 + arow;
        float bv = bias[col];
#pragma unroll
        for (int h = 0; h < 2; ++h) {
#pragma unroll
            for (int i = 0; i < 4; ++i) {
                int row = r0 + h * 16 + kgrp * 4 + i;
                if (row < M) {
                    float v = acc[h][n][i] + bv;
                    if (RELU) v = fmaxf(v, 0.f);
                    if (OUT_BF16)
                        ((unsigned short*)outp)[(size_t)row * NCOL + col] = f2bf(v);
                    else
                        ((float*)outp)[(size_t)row * NCOL + col] = v;
                }
            }
        }
    }
}

// ---------------- launch ----------------

extern "C" void kernel_launch(void* const* d_in, const int* in_sizes, int n_in,
                              void* d_out, int out_size, void* d_ws, size_t ws_size,
                              hipStream_t stream) {
    const float* x   = (const float*)d_in[0];
    const int*   ei  = (const int*)d_in[1];
    const float* W1l = (const float*)d_in[2];
    const float* W1r = (const float*)d_in[3];
    const float* b1  = (const float*)d_in[4];
    const float* W2l = (const float*)d_in[5];
    const float* W2r = (const float*)d_in[6];
    const float* b2  = (const float*)d_in[7];
    float* out = (float*)d_out;

    const int N = in_sizes[0] / 128;  // 50000
    const int E = in_sizes[1] / 2;    // 800000
    const int* src = ei;
    const int* dst = ei + E;

    char* ws = (char*)d_ws;
    size_t off = 0;
    auto carve = [&](size_t bytes) {
        void* p = ws + off;
        off += (bytes + 255) & ~(size_t)255;
        return p;
    };
    int* deg       = (int*)carve((size_t)2 * N * 4);  // deg + cursor, one memset
    int* cursor    = deg + N;
    int* row_start = (int*)carve((size_t)N * 4);
    float* inv_deg = (float*)carve((size_t)N * 4);
    int* partials  = (int*)carve(256 * 4);
    int* csr_src   = (int*)carve((size_t)E * 4);
    int* csr_dst   = (int*)carve((size_t)E * 4);
    unsigned short* xb = (unsigned short*)carve((size_t)N * 128 * 2);
    unsigned short* hb = (unsigned short*)carve((size_t)N * 128 * 2);
    float* aggf        = (float*)carve((size_t)N * 128 * 4);
    unsigned short* P1l = (unsigned short*)carve(128 * 128 * 2);
    unsigned short* P1r = (unsigned short*)carve(128 * 128 * 2);
    unsigned short* P2l = (unsigned short*)carve(128 * 64 * 2);
    unsigned short* P2r = (unsigned short*)carve(128 * 64 * 2);

    hipMemsetAsync(deg, 0, (size_t)2 * N * 4, stream);
    hipMemsetAsync(aggf, 0, (size_t)N * 128 * 4, stream);

    // prep: x -> bf16 + all W packs
    const int nquad = N * 128 / 4;
    prep_kernel<<<(nquad + 49152 + BLK - 1) / BLK, BLK, 0, stream>>>(
        x, xb, nquad, W1l, W1r, W2l, W2r, P1l, P1r, P2l, P2r);

    // CSR build
    const int range = (N + 7) / 8;          // 6250
    const int NCHUNKS = 512;
    const int CH = (E + NCHUNKS - 1) / NCHUNKS;
    deg_xcd_kernel<<<8 * NCHUNKS, BLK, 0, stream>>>(dst, E, deg, range, CH);

    const int nchunk = (N + BLK - 1) / BLK;  // 196 (<=256)
    partial_sum_kernel<<<nchunk, BLK, 0, stream>>>(deg, N, partials);
    scan_partials_kernel<<<1, BLK, 0, stream>>>(partials, nchunk);
    chunk_scan_kernel<<<nchunk, BLK, 0, stream>>>(deg, partials, N, row_start, inv_deg);

    fill_xcd_kernel<<<8 * NCHUNKS, BLK, 0, stream>>>(src, dst, E, row_start, cursor,
                                                     csr_src, csr_dst, range, CH);

    const int aggGrid = (E / 64 + 3) / 4;   // 64 edges per wave, 4 waves/block
    const int gemmGrid = (N + 127) / 128;

    // layer 1: hb = relu(agg(x)@W1l + b1 + x@W1r)
    agg_edge_kernel<<<aggGrid, BLK, 0, stream>>>(xb, csr_src, csr_dst, inv_deg, aggf, E);
    gemm_dual_kernel<128, true, true><<<gemmGrid, BLK, 0, stream>>>(aggf, xb, P1l, P1r, b1, hb, N);
    // layer 2: out = agg(h)@W2l + b2 + h@W2r
    hipMemsetAsync(aggf, 0, (size_t)N * 128 * 4, stream);
    agg_edge_kernel<<<aggGrid, BLK, 0, stream>>>(hb, csr_src, csr_dst, inv_deg, aggf, E);
    gemm_dual_kernel<64, false, false><<<gemmGrid, BLK, 0, stream>>>(aggf, hb, P2l, P2r, b2, out, N);
}

// Round 11
// 272.002 us; speedup vs baseline: 1.2677x; 1.2677x over previous
//
#include <hip/hip_runtime.h>
#include <hip/hip_bf16.h>

// GraphSAGE 2-layer forward on MI355X — round 11.
// Round-8 structure (best measured: 265us) + dispatch-count reduction:
// the three scan kernels are fused into one single-pass lookback scan
// (196 blocks, all co-resident; device-scope acquire/release flags).
// agg = round-8 scalarized-gather (best of 5 agg structures tried).
// 9 dispatches + 1 memset total (was 12).

#define BLK 256

typedef __attribute__((ext_vector_type(8))) short short8;
typedef __attribute__((ext_vector_type(4))) float f32x4;

__device__ inline unsigned short f2bf(float f) {
    unsigned int u = __builtin_bit_cast(unsigned int, f);
    u += 0x7fffu + ((u >> 16) & 1u);  // RNE (inputs finite)
    return (unsigned short)(u >> 16);
}
__device__ inline float bf2f(unsigned short h) {
    return __builtin_bit_cast(float, ((unsigned int)h) << 16);
}

// ---------------- CSR build ----------------

__global__ __launch_bounds__(BLK) void deg_count_kernel(const int* __restrict__ dst,
                                                        int E, int* __restrict__ deg) {
    int e = blockIdx.x * BLK + threadIdx.x;
    if (e < E) atomicAdd(&deg[dst[e]], 1);
}

// Single-pass exclusive scan of deg[n] -> row_start[n] (lookback).
// Grid = ceil(n/BLK) = 196 blocks <= 256 CUs -> all co-resident, spin is safe.
// bflag must be zeroed before launch (covered by the deg memset region).
__global__ __launch_bounds__(BLK) void scan_fused_kernel(const int* __restrict__ deg, int n,
                                                         int* __restrict__ row_start,
                                                         int* __restrict__ bsum,
                                                         int* __restrict__ bflag) {
    __shared__ int s[BLK];
    const int t = threadIdx.x, b = blockIdx.x;
    const int idx = b * BLK + t;
    int v = (idx < n) ? deg[idx] : 0;
    s[t] = v;
    __syncthreads();
    int sum = v;
    for (int o = 1; o < BLK; o <<= 1) {
        int other = (t >= o) ? s[t - o] : 0;
        __syncthreads();
        sum += other;
        s[t] = sum;
        __syncthreads();
    }
    int total = s[BLK - 1];
    if (t == 0) {
        __hip_atomic_store(&bsum[b], total, __ATOMIC_RELAXED, __HIP_MEMORY_SCOPE_AGENT);
        __hip_atomic_store(&bflag[b], 1, __ATOMIC_RELEASE, __HIP_MEMORY_SCOPE_AGENT);
    }
    __syncthreads();  // s[] about to be reused
    // gather predecessor block sums (device-scope acquire pairs with release)
    int pred = 0;
    if (t < b) {
        while (__hip_atomic_load(&bflag[t], __ATOMIC_ACQUIRE, __HIP_MEMORY_SCOPE_AGENT) == 0) {}
        pred = __hip_atomic_load(&bsum[t], __ATOMIC_RELAXED, __HIP_MEMORY_SCOPE_AGENT);
    }
    s[t] = pred;
    __syncthreads();
    for (int o = BLK / 2; o > 0; o >>= 1) {
        if (t < o) s[t] += s[t + o];
        __syncthreads();
    }
    const int base = s[0];
    if (idx < n) row_start[idx] = base + sum - v;  // exclusive
}

// XCD-partitioned fill: blockIdx&7 owns a dst octant so csr/cursor writes for
// that octant stay in one XCD's L2 and merge before writeback.
__global__ __launch_bounds__(BLK) void fill_xcd_kernel(const int* __restrict__ src,
                                                       const int* __restrict__ dst, int E,
                                                       const int* __restrict__ row_start,
                                                       int* __restrict__ cursor,
                                                       int* __restrict__ csr_src,
                                                       int range, int CH) {
    const int oct = blockIdx.x & 7;
    const int chunk = blockIdx.x >> 3;
    const int lo = oct * range, hi = lo + range;
    int e0 = chunk * CH;
    int e1 = min(E, e0 + CH);
    for (int e = e0 + threadIdx.x; e < e1; e += BLK) {
        int d = dst[e];
        if (d >= lo && d < hi) {
            int pos = atomicAdd(&cursor[d], 1);
            csr_src[row_start[d] + pos] = src[e];
        }
    }
}

// ---------------- prep: x f32 -> bf16 row-major + all W packs, one dispatch ----
// P[((kb*(Ncol/16)+n16)*64 + lane)*8 + j] = W[kb*32 + (lane>>4)*8 + j][n16*16 + (lane&15)]

__global__ __launch_bounds__(BLK) void prep_kernel(const float* __restrict__ x,
                                                   unsigned short* __restrict__ xb, int nquad,
                                                   const float* __restrict__ W1l,
                                                   const float* __restrict__ W1r,
                                                   const float* __restrict__ W2l,
                                                   const float* __restrict__ W2r,
                                                   unsigned short* __restrict__ P1l,
                                                   unsigned short* __restrict__ P1r,
                                                   unsigned short* __restrict__ P2l,
                                                   unsigned short* __restrict__ P2r) {
    int t = blockIdx.x * BLK + threadIdx.x;
    if (t < nquad) {
        float4 v = ((const float4*)x)[t];
        ushort4 o;
        o.x = f2bf(v.x); o.y = f2bf(v.y); o.z = f2bf(v.z); o.w = f2bf(v.w);
        ((ushort4*)xb)[t] = o;
        return;
    }
    int w = t - nquad;
    const float* W;
    unsigned short* P;
    int Ncol, local;
    if (w < 16384)      { W = W1l; P = P1l; Ncol = 128; local = w; }
    else if (w < 32768) { W = W1r; P = P1r; Ncol = 128; local = w - 16384; }
    else if (w < 40960) { W = W2l; P = P2l; Ncol = 64;  local = w - 32768; }
    else if (w < 49152) { W = W2r; P = P2r; Ncol = 64;  local = w - 40960; }
    else return;
    int j = local & 7;
    int lane = (local >> 3) & 63;
    int rest = local >> 9;
    int nt = Ncol >> 4;
    int n16 = rest % nt, kb = rest / nt;
    int k = kb * 32 + (lane >> 4) * 8 + j;
    int c = n16 * 16 + (lane & 15);
    P[local] = f2bf(W[(size_t)k * Ncol + c]);
}

// ---------------- scalarized-gather mean aggregation (round-8 best) ----------------
// One wave per node, 64 lanes cover one 256B bf16 row (1 uint = 2 bf16/lane).
// Neighbor index -> SGPR (readlane, wave-uniform slot) -> scalar row base ->
// 16 independent global loads in flight. Masked-16 chunks: slots past cnt
// re-read edge m-1's row (same cache lines, ~free) with weight 0; 1/deg is
// folded into the fmaf so there is no final divide.

__global__ __launch_bounds__(BLK) void agg_mlp_kernel(const unsigned short* __restrict__ feat,
                                                      const int* __restrict__ row_start,
                                                      const int* __restrict__ deg,
                                                      const int* __restrict__ csr_src,
                                                      unsigned short* __restrict__ out,
                                                      int N, int E) {
    const int wave = threadIdx.x >> 6, lane = threadIdx.x & 63;
    const int node = blockIdx.x * (BLK / 64) + wave;
    if (node >= N) return;
    const int start = __builtin_amdgcn_readfirstlane(row_start[node]);
    int cnt = __builtin_amdgcn_readfirstlane(deg[node]);
    cnt = min(cnt, E);  // defensive bound
    const float inv = 1.0f / fmaxf((float)cnt, 1.0f);
    const unsigned int* fp = (const unsigned int*)feat;  // 64 uints per row

    float a0 = 0.f, a1 = 0.f;
    for (int base = 0; base < cnt; base += 64) {
        int m = cnt - base;
        if (m > 64) m = 64;
        int idxv = csr_src[start + base + (lane < m ? lane : m - 1)];
        for (int e = 0; e < m; e += 16) {
            unsigned int v[16];
#pragma unroll
            for (int j = 0; j < 16; j++) {
                int ee = e + j;
                int sl = ee < m ? ee : m - 1;                       // wave-uniform slot
                int s = __builtin_amdgcn_readlane(idxv, sl);        // SGPR index
                v[j] = fp[(size_t)s * 64 + lane];                   // saddr + lane offset
            }
#pragma unroll
            for (int j = 0; j < 16; j++) {
                float w = (e + j < m) ? inv : 0.0f;                 // wave-uniform weight
                a0 = fmaf(bf2f((unsigned short)v[j]), w, a0);
                a1 = fmaf(bf2f((unsigned short)(v[j] >> 16)), w, a1);
            }
        }
    }
    ((unsigned int*)out)[(size_t)node * 64 + lane] =
        (unsigned int)f2bf(a0) | ((unsigned int)f2bf(a1) << 16);
}

// ---------------- MFMA dual GEMM: out = A1@Pl + A2@Pr + bias ----------------
// A-frag: lane holds row=lane&15 (+16), k=(lane>>4)*8+j contiguous 16B.
// D-frag: col=lane&15, row=(lane>>4)*4+i.

template <int NCOL, bool RELU, bool OUT_BF16>
__global__ __launch_bounds__(BLK) void gemm_dual_kernel(const unsigned short* __restrict__ A1,
                                                        const unsigned short* __restrict__ A2,
                                                        const unsigned short* __restrict__ Pl,
                                                        const unsigned short* __restrict__ Pr,
                                                        const float* __restrict__ bias,
                                                        void* __restrict__ outp, int M) {
    constexpr int NT = NCOL / 16;
    const int wave = threadIdx.x >> 6, lane = threadIdx.x & 63;
    const int r0 = blockIdx.x * 128 + wave * 32;
    const int arow = lane & 15, kgrp = lane >> 4;

    f32x4 acc[2][NT];
#pragma unroll
    for (int h = 0; h < 2; h++)
#pragma unroll
        for (int n = 0; n < NT; n++) acc[h][n] = (f32x4){0.f, 0.f, 0.f, 0.f};

    const int ra = min(r0 + arow, M - 1);
    const int rb = min(r0 + 16 + arow, M - 1);

#pragma unroll
    for (int mat = 0; mat < 2; ++mat) {
        const unsigned short* A = mat ? A2 : A1;
        const unsigned short* P = mat ? Pr : Pl;
        const unsigned short* Aa = A + (size_t)ra * 128 + kgrp * 8;
        const unsigned short* Ab = A + (size_t)rb * 128 + kgrp * 8;
#pragma unroll
        for (int kb = 0; kb < 4; ++kb) {
            short8 afa = *(const short8*)(Aa + kb * 32);
            short8 afb = *(const short8*)(Ab + kb * 32);
            const unsigned short* Pk = P + (size_t)kb * NT * 512 + lane * 8;
#pragma unroll
            for (int n = 0; n < NT; ++n) {
                short8 wf = *(const short8*)(Pk + n * 512);
                acc[0][n] = __builtin_amdgcn_mfma_f32_16x16x32_bf16(afa, wf, acc[0][n], 0, 0, 0);
                acc[1][n] = __builtin_amdgcn_mfma_f32_16x16x32_bf16(afb, wf, acc[1][n], 0, 0, 0);
            }
        }
    }

#pragma unroll
    for (int n = 0; n < NT; ++n) {
        int col = n * 16 + arow;
        float bv = bias[col];
#pragma unroll
        for (int h = 0; h < 2; ++h) {
#pragma unroll
            for (int i = 0; i < 4; ++i) {
                int row = r0 + h * 16 + kgrp * 4 + i;
                if (row < M) {
                    float v = acc[h][n][i] + bv;
                    if (RELU) v = fmaxf(v, 0.f);
                    if (OUT_BF16)
                        ((unsigned short*)outp)[(size_t)row * NCOL + col] = f2bf(v);
                    else
                        ((float*)outp)[(size_t)row * NCOL + col] = v;
                }
            }
        }
    }
}

// ---------------- launch ----------------

extern "C" void kernel_launch(void* const* d_in, const int* in_sizes, int n_in,
                              void* d_out, int out_size, void* d_ws, size_t ws_size,
                              hipStream_t stream) {
    const float* x   = (const float*)d_in[0];
    const int*   ei  = (const int*)d_in[1];
    const float* W1l = (const float*)d_in[2];
    const float* W1r = (const float*)d_in[3];
    const float* b1  = (const float*)d_in[4];
    const float* W2l = (const float*)d_in[5];
    const float* W2r = (const float*)d_in[6];
    const float* b2  = (const float*)d_in[7];
    float* out = (float*)d_out;

    const int N = in_sizes[0] / 128;  // 50000
    const int E = in_sizes[1] / 2;    // 800000
    const int* src = ei;
    const int* dst = ei + E;

    char* ws = (char*)d_ws;
    size_t off = 0;
    auto carve = [&](size_t bytes) {
        void* p = ws + off;
        off += (bytes + 255) & ~(size_t)255;
        return p;
    };
    // deg + cursor + bflag contiguous -> single memset; bsum after (no init needed)
    int* deg       = (int*)carve((size_t)(2 * N + 512) * 4);
    int* cursor    = deg + N;
    int* bflag     = deg + 2 * N;   // 256 ints
    int* bsum      = bflag + 256;   // 256 ints
    int* row_start = (int*)carve((size_t)N * 4);
    int* csr_src   = (int*)carve((size_t)E * 4);
    unsigned short* xb   = (unsigned short*)carve((size_t)N * 128 * 2);
    unsigned short* aggb = (unsigned short*)carve((size_t)N * 128 * 2);
    unsigned short* hb   = (unsigned short*)carve((size_t)N * 128 * 2);
    unsigned short* P1l  = (unsigned short*)carve(128 * 128 * 2);
    unsigned short* P1r  = (unsigned short*)carve(128 * 128 * 2);
    unsigned short* P2l  = (unsigned short*)carve(128 * 64 * 2);
    unsigned short* P2r  = (unsigned short*)carve(128 * 64 * 2);

    hipMemsetAsync(deg, 0, (size_t)(2 * N + 256) * 4, stream);  // deg+cursor+bflag

    // prep: x -> bf16 + all W packs (one dispatch)
    const int nquad = N * 128 / 4;
    prep_kernel<<<(nquad + 49152 + BLK - 1) / BLK, BLK, 0, stream>>>(
        x, xb, nquad, W1l, W1r, W2l, W2r, P1l, P1r, P2l, P2r);

    // CSR build: count -> fused scan -> fill
    deg_count_kernel<<<(E + BLK - 1) / BLK, BLK, 0, stream>>>(dst, E, deg);

    const int nchunk = (N + BLK - 1) / BLK;  // 196 (<=256 required for lookback)
    scan_fused_kernel<<<nchunk, BLK, 0, stream>>>(deg, N, row_start, bsum, bflag);

    const int range = (N + 7) / 8;           // 6250
    const int NCHUNKS = 512;
    const int CH = (E + NCHUNKS - 1) / NCHUNKS;
    fill_xcd_kernel<<<8 * NCHUNKS, BLK, 0, stream>>>(src, dst, E, row_start, cursor,
                                                     csr_src, range, CH);

    const int aggGrid = (N + 3) / 4;   // 1 node per wave, 4 waves/block
    const int gemmGrid = (N + 127) / 128;

    // layer 1: hb = relu(agg(x)@W1l + b1 + x@W1r)   (bf16)
    agg_mlp_kernel<<<aggGrid, BLK, 0, stream>>>(xb, row_start, deg, csr_src, aggb, N, E);
    gemm_dual_kernel<128, true, true><<<gemmGrid, BLK, 0, stream>>>(aggb, xb, P1l, P1r, b1, hb, N);
    // layer 2: out = agg(h)@W2l + b2 + h@W2r        (f32)
    agg_mlp_kernel<<<aggGrid, BLK, 0, stream>>>(hb, row_start, deg, csr_src, aggb, N, E);
    gemm_dual_kernel<64, false, false><<<gemmGrid, BLK, 0, stream>>>(aggb, hb, P2l, P2r, b2, out, N);
}